// Round 19
// baseline (118.457 us; speedup 1.0000x reference)
//
#include <hip/hip_runtime.h>
#include <hip/hip_bf16.h>
#include <math.h>

// Problem dims (fixed by reference)
#define S_DIM 1024
#define K_DIM 2048
#define D_DIM 4096
// inputs flat == A[d][s] (A = x^T, [4096][1024] f32); embedding E is [2048][4096] f32

// Output layout (flat f32): [loss(1)] [quant(4194304)] [perp(1)] [idx(1024)]
#define OUT_Q    1
#define OUT_PERP (1 + D_DIM * S_DIM)
#define OUT_IDX  (2 + D_DIM * S_DIM)

#define MARGIN 6.0e-3f
#define CONF_GAP 4.5e-3f
#define FLT_BIG 3.4028235e38f

// ---------------- Workspace layout (bytes) ----------------
#define WS_LOSS   0            // loss @0, npairs @16
#define WS_XX     64
#define WS_EE     4160
#define WS_MINP   77888
#define WS_CNT    143424
#define WS_IDX    208960
#define WS_KCAND  213056
#define WS_SCAND  2310208
#define WS_ESTAGE 4407360
#define WS_XSTAGE 21184576
#define WS_BEST   29573184     // 1024 x u64
#define WS_PAIRS  29581376     // 65536 x int2
#define WS_EEP    30105664ull  // 128 dt x 2048 k f32 = 1MB
#define WS_XXP2   31154240ull  // 128 dt x 1024 s f32 = 512KB
#define WS_NEEDED3 31678528ull

// ---------------- Fallback (round-0) layout ----------------
#define FB_LOSS 0
#define FB_XX   4096
#define FB_EE   8192
#define FB_XXP  16384
#define FB_MINV 81920
#define FB_MINI 212992
#define FB_IDX  344064

typedef __attribute__((ext_vector_type(8))) short bf16x8;
typedef __attribute__((ext_vector_type(4))) float f32x4;
typedef __attribute__((ext_vector_type(4))) unsigned int u32x4;

__device__ __forceinline__ unsigned short f2bf(float f) {
    __hip_bfloat16 h = __float2bfloat16(f);
    return *reinterpret_cast<unsigned short*>(&h);
}

__device__ __forceinline__ void gload16(const void* g, void* l) {
    __builtin_amdgcn_global_load_lds(
        (const __attribute__((address_space(1))) unsigned int*)(g),
        (__attribute__((address_space(3))) unsigned int*)(l), 16, 0, 0);
}

__device__ __forceinline__ void nt_store4u(void* p, unsigned int a, unsigned int b,
                                           unsigned int c, unsigned int d) {
    u32x4 v = {a, b, c, d};
    __builtin_nontemporal_store(v, (u32x4*)p);
}
__device__ __forceinline__ void nt_store4f(void* p, float a, float b, float c, float d) {
    f32x4 v = {a, b, c, d};
    __builtin_nontemporal_store(v, (f32x4*)p);
}

// ---------------- round-0 fallback helpers (xx/ee, bitwise round-0 contract) ----------------
__global__ __launch_bounds__(256) void k_xx_part(const float* __restrict__ A, float* __restrict__ xxp) {
    const int dc = blockIdx.x;
    const int s = blockIdx.y * 256 + threadIdx.x;
    float acc = 0.f;
    for (int dd = 0; dd < 256; ++dd) {
        const int d = dc * 256 + dd;
        float v = A[(size_t)d * S_DIM + s];
        acc = fmaf(v, v, acc);
    }
    xxp[dc * S_DIM + s] = acc;
}

__global__ __launch_bounds__(256) void k_xx_comb(const float* __restrict__ xxp, float* __restrict__ xx) {
    const int s = blockIdx.x * 256 + threadIdx.x;
    float acc = 0.f;
    for (int dc = 0; dc < 16; ++dc) acc += xxp[dc * S_DIM + s];
    xx[s] = acc;
}

__global__ __launch_bounds__(256) void k_ee(const float* __restrict__ E, float* __restrict__ ee) {
    const int k = blockIdx.x;
    const float4* row = (const float4*)(E + (size_t)k * D_DIM);
    float acc = 0.f;
#pragma unroll
    for (int j = 0; j < 4; ++j) {
        float4 v = row[threadIdx.x + j * 256];
        acc = fmaf(v.x, v.x, acc);
        acc = fmaf(v.y, v.y, acc);
        acc = fmaf(v.z, v.z, acc);
        acc = fmaf(v.w, v.w, acc);
    }
    __shared__ float red[256];
    red[threadIdx.x] = acc;
    __syncthreads();
    for (int off = 128; off > 0; off >>= 1) {
        if (threadIdx.x < off) red[threadIdx.x] += red[threadIdx.x + off];
        __syncthreads();
    }
    if (threadIdx.x == 0) ee[k] = red[0];
}

// ---------------- fused conv (nontemporal stage/AT stores: cross-XCD consumers) ----------------
__global__ __launch_bounds__(256) void k_conv(const float* __restrict__ E, const float* __restrict__ A,
                                              float* __restrict__ AT, char* __restrict__ Estage,
                                              char* __restrict__ Xstage, float* __restrict__ eep,
                                              float* __restrict__ xxp2) {
    __shared__ float ldsT[32][65];
    const int dt = blockIdx.x;   // 0..127
    const int tid = threadIdx.x;
    if (blockIdx.y < 16) {
        const int kt = blockIdx.y;
        char* tile = Estage + (size_t)kt * 1048576 + (size_t)dt * 8192;
#pragma unroll
        for (int i = 0; i < 2; ++i) {
            int idx = i * 256 + tid;
            int row = idx >> 2, dc = idx & 3;
            const float4* src = (const float4*)(E + (size_t)(kt * 128 + row) * D_DIM + dt * 32 + dc * 8);
            float4 v0 = src[0], v1 = src[1];
            float vals[8] = {v0.x, v0.y, v0.z, v0.w, v1.x, v1.y, v1.z, v1.w};
            unsigned int w[4];
#pragma unroll
            for (int q = 0; q < 4; ++q)
                w[q] = (unsigned int)f2bf(vals[2 * q]) | ((unsigned int)f2bf(vals[2 * q + 1]) << 16);
            int c_dst = ((row >> 6) * 4 + ((row >> 4) & 3)) * 64 + dc * 16 + (row & 15);
            nt_store4u(tile + (size_t)c_dst * 16, w[0], w[1], w[2], w[3]);
            float p = 0.f;
#pragma unroll
            for (int q = 0; q < 8; ++q) p = fmaf(vals[q], vals[q], p);
            p += __shfl_down(p, 2);
            p += __shfl_down(p, 1);
            if ((tid & 3) == 0) eep[(size_t)dt * K_DIM + kt * 128 + row] = p;
        }
    } else {
        const int st = blockIdx.y - 16;
#pragma unroll
        for (int i = 0; i < 2; ++i) {
            int idx = i * 256 + tid;
            int row_d = idx >> 4, c = idx & 15;
            float4 v = *(const float4*)(A + (size_t)(dt * 32 + row_d) * S_DIM + st * 64 + c * 4);
            ldsT[row_d][c * 4 + 0] = v.x;
            ldsT[row_d][c * 4 + 1] = v.y;
            ldsT[row_d][c * 4 + 2] = v.z;
            ldsT[row_d][c * 4 + 3] = v.w;
        }
        __syncthreads();
        {   // A_T f32 + xx partial (4 lanes per s)
            int s_row = tid >> 2, dpart = (tid & 3) * 8;
            float vals[8];
#pragma unroll
            for (int j = 0; j < 8; ++j) vals[j] = ldsT[dpart + j][s_row];
            float* dst = AT + (size_t)(st * 64 + s_row) * D_DIM + dt * 32 + dpart;
            nt_store4f(dst + 0, vals[0], vals[1], vals[2], vals[3]);
            nt_store4f(dst + 4, vals[4], vals[5], vals[6], vals[7]);
            float p = 0.f;
#pragma unroll
            for (int j = 0; j < 8; ++j) p = fmaf(vals[j], vals[j], p);
            p += __shfl_down(p, 2);
            p += __shfl_down(p, 1);
            if ((tid & 3) == 0) xxp2[(size_t)dt * S_DIM + st * 64 + s_row] = p;
        }
        {   // bf16 stage tile in fragment order
            int s_row = tid >> 2, dc = tid & 3;
            float vals[8];
#pragma unroll
            for (int j = 0; j < 8; ++j) vals[j] = ldsT[dc * 8 + j][s_row];
            unsigned int w[4];
#pragma unroll
            for (int q = 0; q < 4; ++q)
                w[q] = (unsigned int)f2bf(vals[2 * q]) | ((unsigned int)f2bf(vals[2 * q + 1]) << 16);
            int gn = ((s_row >> 5) << 1) | ((s_row >> 4) & 1);
            int c_dst = gn * 64 + dc * 16 + (s_row & 15);
            char* tile = Xstage + (size_t)st * 524288 + (size_t)dt * 4096;
            nt_store4u(tile + (size_t)c_dst * 16, w[0], w[1], w[2], w[3]);
        }
    }
}

// ---------------- combine partials + init best sentinels ----------------
__global__ __launch_bounds__(256) void k_sums(const float* __restrict__ eep, const float* __restrict__ xxp2,
                                              float* __restrict__ ee, float* __restrict__ xx,
                                              unsigned long long* __restrict__ best) {
    const int gid = blockIdx.x * 256 + threadIdx.x;
    if (gid < 1024) best[gid] = 0xFFFFFFFFFFFFFFFFull;
    if (gid < K_DIM) {
        float a = 0.f;
        for (int dt = 0; dt < 128; ++dt) a += eep[(size_t)dt * K_DIM + gid];
        ee[gid] = a;
    } else if (gid < K_DIM + S_DIM) {
        const int s = gid - K_DIM;
        float a = 0.f;
        for (int dt = 0; dt < 128; ++dt) a += xxp2[(size_t)dt * S_DIM + s];
        xx[s] = a;
    }
}

// ---------------- MFMA filter GEMM v5 (round-16 best): in-block K-split x4, 16 waves ----------------
__global__ __launch_bounds__(1024) void k_gemm_score5(const char* __restrict__ Estage, const char* __restrict__ Xstage,
                                                      const float* __restrict__ xx, const float* __restrict__ ee,
                                                      float* __restrict__ minp, int* __restrict__ cnt,
                                                      int* __restrict__ kcand, float* __restrict__ scand) {
    __shared__ short lds[4 * 3 * 6144];   // 147456 B; reused as f32x4 for acc reduce
    __shared__ float minw[2][64];
    __shared__ float minb[64];
    __shared__ int cntl[64];

    // XCD swizzle: 4 ktb x 8 st per XCD (bijective)
    const int linear = blockIdx.y * 16 + blockIdx.x;
    const int xcd = linear & 7, ii = linear >> 3;      // ii in [0,32)
    const int ktb = (xcd >> 1) * 4 + (ii >> 3);
    const int st  = (xcd & 1) * 8 + (ii & 7);

    const int tid = threadIdx.x;       // 0..1023
    const int h = tid >> 8;            // K-quarter 0..3
    const int tidh = tid & 255;
    const int wid2 = tidh >> 6;
    const int wm = wid2 >> 1;          // k half (64)
    const int wn = wid2 & 1;           // s half (32)
    const int lane = tid & 63;
    const int lr = lane & 15;
    const int lh = lane >> 4;

    const char* Eb = Estage + (size_t)ktb * 1048576;
    const char* Xb = Xstage + (size_t)st * 524288;
    short* myl = lds + h * 18432;      // this quarter's 3 slots x 6144 shorts

    f32x4 acc[4][2];
#pragma unroll
    for (int f = 0; f < 4; ++f)
#pragma unroll
        for (int g = 0; g < 2; ++g) acc[f][g] = (f32x4){0.f, 0.f, 0.f, 0.f};

#define STG(t, sl) { \
    const char* eb_ = Eb + (size_t)(h * 32 + (t)) * 8192; \
    char* d_ = (char*)myl + (sl) * 12288; \
    gload16(eb_ + tidh * 16, d_ + tidh * 16); \
    gload16(eb_ + 4096 + tidh * 16, d_ + 4096 + tidh * 16); \
    gload16(Xb + (size_t)(h * 32 + (t)) * 4096 + tidh * 16, d_ + 8192 + tidh * 16); }

#define CMP(sl) { \
    const short* s_ = myl + (sl) * 6144; \
    bf16x8 af[4], bx[2]; \
    _Pragma("unroll") \
    for (int f = 0; f < 4; ++f) af[f] = *(const bf16x8*)(s_ + (wm * 4 + f) * 512 + lane * 8); \
    _Pragma("unroll") \
    for (int g = 0; g < 2; ++g) bx[g] = *(const bf16x8*)(s_ + 4096 + (wn * 2 + g) * 512 + lane * 8); \
    _Pragma("unroll") \
    for (int f = 0; f < 4; ++f) { \
        _Pragma("unroll") \
        for (int g = 0; g < 2; ++g) \
            acc[f][g] = __builtin_amdgcn_mfma_f32_16x16x32_bf16(af[f], bx[g], acc[f][g], 0, 0, 0); \
    } }

#define WB(nstr) asm volatile("s_waitcnt vmcnt(" nstr ")\n\ts_barrier" ::: "memory")
#define BAR asm volatile("s_barrier" ::: "memory")

    STG(0, 0) STG(1, 1)

    for (int bb = 0; bb < 30; bb += 3) {
        STG(bb + 2, 2) WB("6"); CMP(0) BAR;
        STG(bb + 3, 0) WB("6"); CMP(1) BAR;
        STG(bb + 4, 1) WB("6"); CMP(2) BAR;
    }
    // staged 0..31, computed 0..29
    WB("3"); CMP(0) BAR;   // c30
    WB("0"); CMP(1)        // c31
    __syncthreads();

#undef STG
#undef CMP
#undef WB
#undef BAR

    // cross-quarter acc reduction via LDS (fixed ascending order, deterministic)
    f32x4* red4 = (f32x4*)lds;
    if (h != 0) {
#pragma unroll
        for (int f = 0; f < 4; ++f)
#pragma unroll
            for (int g = 0; g < 2; ++g)
                red4[(size_t)(h - 1) * 2048 + (f * 2 + g) * 256 + tidh] = acc[f][g];
    }
    __syncthreads();
    if (h == 0) {
#pragma unroll
        for (int q = 1; q < 4; ++q)
#pragma unroll
            for (int f = 0; f < 4; ++f)
#pragma unroll
                for (int g = 0; g < 2; ++g)
                    acc[f][g] += red4[(size_t)(q - 1) * 2048 + (f * 2 + g) * 256 + tidh];
    }

    // epilogue (round-10, validated): sc = (xx - 2*xe) + ee
    float xs[2], ek[4][4];
#pragma unroll
    for (int g = 0; g < 2; ++g) xs[g] = xx[st * 64 + wn * 32 + g * 16 + lr];
#pragma unroll
    for (int f = 0; f < 4; ++f)
#pragma unroll
        for (int r = 0; r < 4; ++r) ek[f][r] = ee[ktb * 128 + wm * 64 + f * 16 + lh * 4 + r];

    float mg[2] = {FLT_BIG, FLT_BIG};
#pragma unroll
    for (int f = 0; f < 4; ++f)
#pragma unroll
        for (int g = 0; g < 2; ++g)
#pragma unroll
            for (int r = 0; r < 4; ++r) {
                float sc = (xs[g] - 2.0f * acc[f][g][r]) + ek[f][r];
                mg[g] = fminf(mg[g], sc);
            }
#pragma unroll
    for (int g = 0; g < 2; ++g) {
        mg[g] = fminf(mg[g], __shfl_xor(mg[g], 16));
        mg[g] = fminf(mg[g], __shfl_xor(mg[g], 32));
    }
    if (h == 0 && lane < 16) {
        minw[wm][wn * 32 + lane] = mg[0];
        minw[wm][wn * 32 + 16 + lane] = mg[1];
    }
    __syncthreads();
    if (tid < 64) {
        float mb = fminf(minw[0][tid], minw[1][tid]);
        minb[tid] = mb;
        minp[ktb * S_DIM + st * 64 + tid] = mb;
        cntl[tid] = 0;
    }
    __syncthreads();
    if (h == 0) {
#pragma unroll
        for (int f = 0; f < 4; ++f)
#pragma unroll
            for (int g = 0; g < 2; ++g)
#pragma unroll
                for (int r = 0; r < 4; ++r) {
                    float sc = (xs[g] - 2.0f * acc[f][g][r]) + ek[f][r];
                    int sl = wn * 32 + g * 16 + lr;
                    if (sc <= minb[sl] + MARGIN) {
                        int slot = atomicAdd(&cntl[sl], 1);
                        if (slot < 32) {
                            int si = ktb * S_DIM + st * 64 + sl;
                            kcand[si * 32 + slot] = ktb * 128 + wm * 64 + f * 16 + lh * 4 + r;
                            scand[si * 32 + slot] = sc;
                        }
                    }
                }
    }
    __syncthreads();
    if (tid < 64) cnt[ktb * S_DIM + st * 64 + tid] = min(cntl[tid], 32);
}

// ---------------- gate: confident shortcut or emit PRUNED (s,k) pairs ----------------
__global__ __launch_bounds__(64) void k_select_gate(const float* __restrict__ minp, const int* __restrict__ cnt,
                                                    const int* __restrict__ kcand, const float* __restrict__ scand,
                                                    int* __restrict__ idx, float* __restrict__ out,
                                                    int* __restrict__ npairs, int2* __restrict__ pairs) {
    __shared__ int   lcand[64];
    __shared__ float lsc[64];
    __shared__ int   lcount;
    const int s = blockIdx.x;
    const int lane = threadIdx.x;
    if (lane == 0) lcount = 0;

    float mv = (lane < 16) ? minp[lane * S_DIM + s] : FLT_BIG;
#pragma unroll
    for (int off = 1; off < 64; off <<= 1) mv = fminf(mv, __shfl_xor(mv, off));
    const float m_a = mv;

    int myc = (lane < 16) ? cnt[lane * S_DIM + s] : 0;
    float gsc[16]; int gkc[16]; int gcs[16];
#pragma unroll
    for (int kt = 0; kt < 16; ++kt) {
        int c = __shfl(myc, kt);
        gcs[kt] = c;
        gsc[kt] = FLT_BIG; gkc[kt] = 0;
        if (lane < c) {
            gsc[kt] = scand[(kt * S_DIM + s) * 32 + lane];
            gkc[kt] = kcand[(kt * S_DIM + s) * 32 + lane];
        }
    }
#pragma unroll
    for (int kt = 0; kt < 16; ++kt) {
        if (lane < gcs[kt] && gsc[kt] <= m_a + MARGIN) {
            int slot = atomicAdd(&lcount, 1);
            if (slot < 64) { lcand[slot] = gkc[kt]; lsc[slot] = gsc[kt]; }
        }
    }
    __syncthreads();
    const int n = min(lcount, 64);

    float bv = (lane < n) ? lsc[lane] : FLT_BIG;
    int   bk = (lane < n) ? lcand[lane] : 0x7fffffff;
#pragma unroll
    for (int off = 1; off < 64; off <<= 1) {
        float ov = __shfl_xor(bv, off); int ok = __shfl_xor(bk, off);
        if (ov < bv || (ov == bv && ok < bk)) { bv = ov; bk = ok; }
    }
    float sv = (lane < n && lcand[lane] != bk) ? lsc[lane] : FLT_BIG;
#pragma unroll
    for (int off = 1; off < 64; off <<= 1) sv = fminf(sv, __shfl_xor(sv, off));

    if (n == 1 || sv - bv > CONF_GAP) {
        if (lane == 0) { idx[s] = bk; out[OUT_IDX + s] = (float)bk; }
        return;
    }

    bool em = (lane < n) && (lsc[lane] <= bv + CONF_GAP);
    unsigned long long m = __ballot(em);
    int cnt2 = __popcll(m);
    int base = 0;
    if (lane == 0) base = atomicAdd(npairs, cnt2);
    base = __shfl(base, 0);
    int off2 = (int)__popcll(m & ((1ull << lane) - 1ull));
    if (em) pairs[base + off2] = make_int2(s, lcand[lane]);
}

// ---------------- per-pair exact chain (bitwise round-0 arithmetic, register-resident) ----------------
__global__ __launch_bounds__(64) void k_pair_chain(const float* __restrict__ AT, const float* __restrict__ E,
                                                   const float* __restrict__ xx, const float* __restrict__ ee,
                                                   const int* __restrict__ npairs, const int2* __restrict__ pairs,
                                                   unsigned long long* __restrict__ best) {
    const int np = min(*npairs, 65536);
    const int lane = threadIdx.x;
    for (int p = blockIdx.x; p < np; p += gridDim.x) {
        int2 pr = pairs[p];
        const float4* er4 = (const float4*)(E + (size_t)pr.y * D_DIM) + lane * 16;
        const float4* xr4 = (const float4*)(AT + (size_t)pr.x * D_DIM) + lane * 16;
        float4 er[16], xr[16];
#pragma unroll
        for (int i = 0; i < 16; ++i) { er[i] = er4[i]; xr[i] = xr4[i]; }

        float c = 0.f;
        for (int seg = 0; seg < 64; ++seg) {
            float cin = __shfl(c, (seg + 63) & 63);
            if (lane == seg) {
                float a = (seg == 0) ? 0.f : cin;
#pragma unroll
                for (int i = 0; i < 16; ++i) {
                    a = fmaf(er[i].x, xr[i].x, a);
                    a = fmaf(er[i].y, xr[i].y, a);
                    a = fmaf(er[i].z, xr[i].z, a);
                    a = fmaf(er[i].w, xr[i].w, a);
                }
                c = a;
            }
        }
        float dot = __shfl(c, 63);
        if (lane == 0) {
            float u = xx[pr.x] - 2.0f * dot;
            float sc = u + ee[pr.y];
            unsigned long long pk = ((unsigned long long)__float_as_uint(sc) << 32) | (unsigned int)pr.y;
            atomicMin(&best[pr.x], pk);
        }
    }
}

// ---------------- Round-0 fallback GEMM+argmin ----------------
__global__ __launch_bounds__(256) void k_gemm_argmin(const float* __restrict__ A, const float* __restrict__ E,
                                                     const float* __restrict__ xx, const float* __restrict__ ee,
                                                     float* __restrict__ minv, int* __restrict__ mini) {
    __shared__ float Et[32][64];
    __shared__ float At[32][64];
    __shared__ float rv[16][64];
    __shared__ int   ri[16][64];
    const int kt = blockIdx.x, st = blockIdx.y;
    const int k0 = kt * 64, s0 = st * 64;
    const int tid = threadIdx.x;
    const int tcol = tid & 15, trow = tid >> 4;
    float acc[4][4] = {{0.f,0.f,0.f,0.f},{0.f,0.f,0.f,0.f},{0.f,0.f,0.f,0.f},{0.f,0.f,0.f,0.f}};
    for (int dt = 0; dt < D_DIM / 32; ++dt) {
        const int d0 = dt * 32;
        __syncthreads();
#pragma unroll
        for (int it = 0; it < 2; ++it) {
            int f = tid + it * 256;
            int kk = f >> 3, dd4 = f & 7;
            float4 v = *(const float4*)(E + (size_t)(k0 + kk) * D_DIM + d0 + dd4 * 4);
            Et[dd4 * 4 + 0][kk] = v.x; Et[dd4 * 4 + 1][kk] = v.y;
            Et[dd4 * 4 + 2][kk] = v.z; Et[dd4 * 4 + 3][kk] = v.w;
        }
#pragma unroll
        for (int it = 0; it < 2; ++it) {
            int f = tid + it * 256;
            int ss4 = f & 15, dd = f >> 4;
            float4 v = *(const float4*)(A + (size_t)(d0 + dd) * S_DIM + s0 + ss4 * 4);
            *(float4*)&At[dd][ss4 * 4] = v;
        }
        __syncthreads();
#pragma unroll 8
        for (int dd = 0; dd < 32; ++dd) {
            float4 a4 = *(const float4*)&At[dd][tcol * 4];
            float4 e4 = *(const float4*)&Et[dd][trow * 4];
            float a[4] = {a4.x, a4.y, a4.z, a4.w};
            float e[4] = {e4.x, e4.y, e4.z, e4.w};
#pragma unroll
            for (int i = 0; i < 4; ++i)
#pragma unroll
                for (int j = 0; j < 4; ++j) acc[i][j] = fmaf(e[i], a[j], acc[i][j]);
        }
    }
    float xs[4], ek[4];
#pragma unroll
    for (int j = 0; j < 4; ++j) xs[j] = xx[s0 + tcol * 4 + j];
#pragma unroll
    for (int i = 0; i < 4; ++i) ek[i] = ee[k0 + trow * 4 + i];
#pragma unroll
    for (int j = 0; j < 4; ++j) {
        float bv = FLT_BIG; int bk = 0x7fffffff;
#pragma unroll
        for (int i = 0; i < 4; ++i) {
            float xe = acc[i][j];
            float u = xs[j] - 2.0f * xe;
            float sc = u + ek[i];
            int k = k0 + trow * 4 + i;
            if (sc < bv) { bv = sc; bk = k; }
        }
        rv[trow][tcol * 4 + j] = bv;
        ri[trow][tcol * 4 + j] = bk;
    }
    __syncthreads();
    if (tid < 64) {
        float bv = rv[0][tid]; int bk = ri[0][tid];
#pragma unroll
        for (int r = 1; r < 16; ++r) {
            float v = rv[r][tid]; int k2 = ri[r][tid];
            if (v < bv || (v == bv && k2 < bk)) { bv = v; bk = k2; }
        }
        minv[kt * S_DIM + s0 + tid] = bv;
        mini[kt * S_DIM + s0 + tid] = bk;
    }
}

__global__ __launch_bounds__(256) void k_argmin_final(const float* __restrict__ minv, const int* __restrict__ mini,
                                                      int* __restrict__ idx, float* __restrict__ out) {
    const int s = blockIdx.x * 256 + threadIdx.x;
    float bv = minv[s];
    int bk = mini[s];
    for (int kt = 1; kt < 32; ++kt) {
        float v = minv[kt * S_DIM + s];
        int k2 = mini[kt * S_DIM + s];
        if (v < bv || (v == bv && k2 < bk)) { bv = v; bk = k2; }
    }
    idx[s] = bk;
    out[OUT_IDX + s] = (float)bk;
}

// ---------------- STE output + loss + fused fin: 128-d tiles, 4 blocks/CU ----------------
// Grid (16 st, 32 db). qt[64][133] = 34KB -> 4 blocks/CU (2x round-18 latency hiding);
// gather granule 512B contiguous per E row; stride 133 (odd) -> conflict-free columns.
// Elementwise arithmetic identical to all passing rounds.
__global__ __launch_bounds__(256) void k_output_loss2(const float* __restrict__ A, const float* __restrict__ E,
                                                      const int* __restrict__ idx,
                                                      const unsigned long long* __restrict__ best,
                                                      float* __restrict__ out, float* __restrict__ loss) {
    __shared__ float qt[64][133];   // 34 KB
    __shared__ int sidx[64];
    __shared__ float red[256];
    const int st = blockIdx.x, db = blockIdx.y;
    const int s0 = st * 64, d0 = db * 128;
    const int tid = threadIdx.x;
    if (tid < 64) {
        const int s = s0 + tid;
        unsigned long long b = best[s];
        int k;
        if (b != 0xFFFFFFFFFFFFFFFFull) {
            k = (int)(b & 0xFFFFFFFFu);
            if (db == 0) out[OUT_IDX + s] = (float)k;   // non-confident s: fin fused here
        } else {
            k = idx[s];                                  // confident s: gate wrote idx+out
        }
        sidx[tid] = k;
    }
    __syncthreads();
    // stage 64 rows x 128 floats: chunk c = i*256+tid; 512B contiguous per E row
#pragma unroll
    for (int i = 0; i < 8; ++i) {
        int c = i * 256 + tid;
        int si = c >> 5, c4 = c & 31;
        float4 v = *(const float4*)(E + (size_t)sidx[si] * D_DIM + d0 + c4 * 4);
        qt[si][c4 * 4 + 0] = v.x; qt[si][c4 * 4 + 1] = v.y;
        qt[si][c4 * 4 + 2] = v.z; qt[si][c4 * 4 + 3] = v.w;
    }
    __syncthreads();
    const int ss = tid & 63;
    const int dg = tid >> 6;
    float lsum = 0.f;
#pragma unroll 8
    for (int i = 0; i < 32; ++i) {
        const int dd = dg * 32 + i;
        const int d = d0 + dd;
        float x = A[(size_t)d * S_DIM + s0 + ss];
        float q = qt[ss][dd];
        float diff = q - x;
        float val = x + diff;
        out[OUT_Q + (size_t)d * S_DIM + s0 + ss] = val;
        lsum = fmaf(diff, diff, lsum);
    }
    red[tid] = lsum;
    __syncthreads();
    for (int off = 128; off > 0; off >>= 1) {
        if (tid < off) red[tid] += red[tid + off];
        __syncthreads();
    }
    if (tid == 0) atomicAdd(loss, red[0]);
}

// ---------------- fallback STE output + loss ----------------
__global__ __launch_bounds__(256) void k_output_loss(const float* __restrict__ A, const float* __restrict__ E,
                                                     const int* __restrict__ idx, float* __restrict__ out,
                                                     float* __restrict__ loss) {
    __shared__ float qt[64][65];
    __shared__ int sidx[64];
    __shared__ float red[256];
    const int st = blockIdx.x, dtb = blockIdx.y;
    const int s0 = st * 64, d0 = dtb * 64;
    const int tid = threadIdx.x;
    if (tid < 64) sidx[tid] = idx[s0 + tid];
    __syncthreads();
#pragma unroll
    for (int it = 0; it < 4; ++it) {
        int f = tid + it * 256;
        int si = f >> 4, c4 = f & 15;
        float4 v = *(const float4*)(E + (size_t)sidx[si] * D_DIM + d0 + c4 * 4);
        qt[si][c4 * 4 + 0] = v.x; qt[si][c4 * 4 + 1] = v.y;
        qt[si][c4 * 4 + 2] = v.z; qt[si][c4 * 4 + 3] = v.w;
    }
    __syncthreads();
    const int ss = tid & 63;
    const int dg = tid >> 6;
    float lsum = 0.f;
#pragma unroll
    for (int i = 0; i < 16; ++i) {
        const int dd = dg * 16 + i;
        const int d = d0 + dd;
        float x = A[(size_t)d * S_DIM + s0 + ss];
        float q = qt[ss][dd];
        float diff = q - x;
        float val = x + diff;
        out[OUT_Q + (size_t)d * S_DIM + s0 + ss] = val;
        lsum = fmaf(diff, diff, lsum);
    }
    red[tid] = lsum;
    __syncthreads();
    for (int off = 128; off > 0; off >>= 1) {
        if (tid < off) red[tid] += red[tid + off];
        __syncthreads();
    }
    if (tid == 0) atomicAdd(loss, red[0]);
}

__global__ void k_scalars(const float* __restrict__ loss, float* __restrict__ out) {
    out[0] = 1.25f * loss[0] * (1.0f / (float)(S_DIM * D_DIM));
    out[OUT_PERP] = 1.0f;
}

extern "C" void kernel_launch(void* const* d_in, const int* in_sizes, int n_in,
                              void* d_out, int out_size, void* d_ws, size_t ws_size,
                              hipStream_t stream) {
    const float* A = (const float*)d_in[0];
    const float* E = (const float*)d_in[1];
    float* out = (float*)d_out;
    char* ws = (char*)d_ws;

    if (ws_size >= WS_NEEDED3) {
        float* w_loss = (float*)(ws + WS_LOSS);
        int*   w_np   = (int*)(ws + 16);
        float* w_xx   = (float*)(ws + WS_XX);
        float* w_ee   = (float*)(ws + WS_EE);
        float* w_minp = (float*)(ws + WS_MINP);
        int*   w_cnt  = (int*)(ws + WS_CNT);
        int*   w_idx  = (int*)(ws + WS_IDX);
        int*   w_kc   = (int*)(ws + WS_KCAND);
        float* w_sc   = (float*)(ws + WS_SCAND);
        char*  w_es   = ws + WS_ESTAGE;
        char*  w_xs   = ws + WS_XSTAGE;
        unsigned long long* w_best = (unsigned long long*)(ws + WS_BEST);
        int2*  w_pairs = (int2*)(ws + WS_PAIRS);
        float* w_eep  = (float*)(ws + WS_EEP);
        float* w_xxp2 = (float*)(ws + WS_XXP2);
        float* AT     = out + OUT_Q;   // park A^T in quant region; overwritten by k_output_loss2

        hipMemsetAsync(ws, 0, 64, stream);                     // loss + npairs
        k_conv<<<dim3(128, 32), 256, 0, stream>>>(E, A, AT, w_es, w_xs, w_eep, w_xxp2);
        k_sums<<<dim3(12), 256, 0, stream>>>(w_eep, w_xxp2, w_ee, w_xx, w_best);
        k_gemm_score5<<<dim3(16, 16), 1024, 0, stream>>>(w_es, w_xs, w_xx, w_ee, w_minp, w_cnt, w_kc, w_sc);
        k_select_gate<<<dim3(S_DIM), 64, 0, stream>>>(w_minp, w_cnt, w_kc, w_sc, w_idx, out, w_np, w_pairs);
        k_pair_chain<<<dim3(2048), 64, 0, stream>>>(AT, E, w_xx, w_ee, w_np, w_pairs, w_best);
        k_output_loss2<<<dim3(16, 32), 256, 0, stream>>>(A, E, w_idx, w_best, out, w_loss);
        k_scalars<<<1, 1, 0, stream>>>(w_loss, out);
    } else {
        // round-0 fallback
        float* w_loss = (float*)(ws + FB_LOSS);
        float* w_xx   = (float*)(ws + FB_XX);
        float* w_ee   = (float*)(ws + FB_EE);
        float* w_xxp  = (float*)(ws + FB_XXP);
        float* w_minv = (float*)(ws + FB_MINV);
        int*   w_mini = (int*)(ws + FB_MINI);
        int*   w_idx  = (int*)(ws + FB_IDX);

        hipMemsetAsync(ws, 0, 256, stream);
        k_xx_part<<<dim3(16, 4), 256, 0, stream>>>(A, w_xxp);
        k_ee<<<dim3(K_DIM), 256, 0, stream>>>(E, w_ee);
        k_xx_comb<<<dim3(4), 256, 0, stream>>>(w_xxp, w_xx);
        k_gemm_argmin<<<dim3(32, 16), 256, 0, stream>>>(A, E, w_xx, w_ee, w_minv, w_mini);
        k_argmin_final<<<dim3(4), 256, 0, stream>>>(w_minv, w_mini, w_idx, out);
        k_output_loss<<<dim3(16, 64), 256, 0, stream>>>(A, E, w_idx, out, w_loss);
        k_scalars<<<1, 1, 0, stream>>>(w_loss, out);
    }
}

// Round 20
// 105.269 us; speedup vs baseline: 1.1253x; 1.1253x over previous
//
#include <hip/hip_runtime.h>
#include <hip/hip_bf16.h>
#include <math.h>

// Problem dims (fixed by reference)
#define S_DIM 1024
#define K_DIM 2048
#define D_DIM 4096
// inputs flat == A[d][s] (A = x^T, [4096][1024] f32); embedding E is [2048][4096] f32

// Output layout (flat f32): [loss(1)] [quant(4194304)] [perp(1)] [idx(1024)]
#define OUT_Q    1
#define OUT_PERP (1 + D_DIM * S_DIM)
#define OUT_IDX  (2 + D_DIM * S_DIM)

#define MARGIN 6.0e-3f
#define CONF_GAP 4.5e-3f
#define FLT_BIG 3.4028235e38f

// ---------------- Workspace layout (bytes) ----------------
#define WS_LOSS   0            // loss @0, npairs @16
#define WS_XX     64
#define WS_EE     4160
#define WS_MINP   77888
#define WS_CNT    143424
#define WS_IDX    208960
#define WS_KCAND  213056
#define WS_SCAND  2310208
#define WS_ESTAGE 4407360
#define WS_XSTAGE 21184576
#define WS_BEST   29573184     // 1024 x u64
#define WS_PAIRS  29581376     // 65536 x int2
#define WS_EEP    30105664ull  // 128 dt x 2048 k f32 = 1MB
#define WS_XXP2   31154240ull  // 128 dt x 1024 s f32 = 512KB
#define WS_NEEDED3 31678528ull

// ---------------- Fallback (round-0) layout ----------------
#define FB_LOSS 0
#define FB_XX   4096
#define FB_EE   8192
#define FB_XXP  16384
#define FB_MINV 81920
#define FB_MINI 212992
#define FB_IDX  344064

typedef __attribute__((ext_vector_type(8))) short bf16x8;
typedef __attribute__((ext_vector_type(4))) float f32x4;

__device__ __forceinline__ unsigned short f2bf(float f) {
    __hip_bfloat16 h = __float2bfloat16(f);
    return *reinterpret_cast<unsigned short*>(&h);
}

__device__ __forceinline__ void gload16(const void* g, void* l) {
    __builtin_amdgcn_global_load_lds(
        (const __attribute__((address_space(1))) unsigned int*)(g),
        (__attribute__((address_space(3))) unsigned int*)(l), 16, 0, 0);
}

// ---------------- round-0 fallback helpers (xx/ee, bitwise round-0 contract) ----------------
__global__ __launch_bounds__(256) void k_xx_part(const float* __restrict__ A, float* __restrict__ xxp) {
    const int dc = blockIdx.x;
    const int s = blockIdx.y * 256 + threadIdx.x;
    float acc = 0.f;
    for (int dd = 0; dd < 256; ++dd) {
        const int d = dc * 256 + dd;
        float v = A[(size_t)d * S_DIM + s];
        acc = fmaf(v, v, acc);
    }
    xxp[dc * S_DIM + s] = acc;
}

__global__ __launch_bounds__(256) void k_xx_comb(const float* __restrict__ xxp, float* __restrict__ xx) {
    const int s = blockIdx.x * 256 + threadIdx.x;
    float acc = 0.f;
    for (int dc = 0; dc < 16; ++dc) acc += xxp[dc * S_DIM + s];
    xx[s] = acc;
}

__global__ __launch_bounds__(256) void k_ee(const float* __restrict__ E, float* __restrict__ ee) {
    const int k = blockIdx.x;
    const float4* row = (const float4*)(E + (size_t)k * D_DIM);
    float acc = 0.f;
#pragma unroll
    for (int j = 0; j < 4; ++j) {
        float4 v = row[threadIdx.x + j * 256];
        acc = fmaf(v.x, v.x, acc);
        acc = fmaf(v.y, v.y, acc);
        acc = fmaf(v.z, v.z, acc);
        acc = fmaf(v.w, v.w, acc);
    }
    __shared__ float red[256];
    red[threadIdx.x] = acc;
    __syncthreads();
    for (int off = 128; off > 0; off >>= 1) {
        if (threadIdx.x < off) red[threadIdx.x] += red[threadIdx.x + off];
        __syncthreads();
    }
    if (threadIdx.x == 0) ee[k] = red[0];
}

// ---------------- fused conv: y<16 -> E tiles + ee partials ; y>=16 -> A_T + X tiles + xx partials ----------------
__global__ __launch_bounds__(256) void k_conv(const float* __restrict__ E, const float* __restrict__ A,
                                              float* __restrict__ AT, char* __restrict__ Estage,
                                              char* __restrict__ Xstage, float* __restrict__ eep,
                                              float* __restrict__ xxp2) {
    __shared__ float ldsT[32][65];
    const int dt = blockIdx.x;   // 0..127
    const int tid = threadIdx.x;
    if (blockIdx.y < 16) {
        const int kt = blockIdx.y;
        char* tile = Estage + (size_t)kt * 1048576 + (size_t)dt * 8192;
#pragma unroll
        for (int i = 0; i < 2; ++i) {
            int idx = i * 256 + tid;
            int row = idx >> 2, dc = idx & 3;
            const float4* src = (const float4*)(E + (size_t)(kt * 128 + row) * D_DIM + dt * 32 + dc * 8);
            float4 v0 = src[0], v1 = src[1];
            float vals[8] = {v0.x, v0.y, v0.z, v0.w, v1.x, v1.y, v1.z, v1.w};
            unsigned int w[4];
#pragma unroll
            for (int q = 0; q < 4; ++q)
                w[q] = (unsigned int)f2bf(vals[2 * q]) | ((unsigned int)f2bf(vals[2 * q + 1]) << 16);
            int c_dst = ((row >> 6) * 4 + ((row >> 4) & 3)) * 64 + dc * 16 + (row & 15);
            *(uint4*)(tile + (size_t)c_dst * 16) = make_uint4(w[0], w[1], w[2], w[3]);
            float p = 0.f;
#pragma unroll
            for (int q = 0; q < 8; ++q) p = fmaf(vals[q], vals[q], p);
            p += __shfl_down(p, 2);
            p += __shfl_down(p, 1);
            if ((tid & 3) == 0) eep[(size_t)dt * K_DIM + kt * 128 + row] = p;
        }
    } else {
        const int st = blockIdx.y - 16;
#pragma unroll
        for (int i = 0; i < 2; ++i) {
            int idx = i * 256 + tid;
            int row_d = idx >> 4, c = idx & 15;
            float4 v = *(const float4*)(A + (size_t)(dt * 32 + row_d) * S_DIM + st * 64 + c * 4);
            ldsT[row_d][c * 4 + 0] = v.x;
            ldsT[row_d][c * 4 + 1] = v.y;
            ldsT[row_d][c * 4 + 2] = v.z;
            ldsT[row_d][c * 4 + 3] = v.w;
        }
        __syncthreads();
        {   // A_T f32 + xx partial (4 lanes per s)
            int s_row = tid >> 2, dpart = (tid & 3) * 8;
            float vals[8];
#pragma unroll
            for (int j = 0; j < 8; ++j) vals[j] = ldsT[dpart + j][s_row];
            float* dst = AT + (size_t)(st * 64 + s_row) * D_DIM + dt * 32 + dpart;
            *(float4*)(dst + 0) = make_float4(vals[0], vals[1], vals[2], vals[3]);
            *(float4*)(dst + 4) = make_float4(vals[4], vals[5], vals[6], vals[7]);
            float p = 0.f;
#pragma unroll
            for (int j = 0; j < 8; ++j) p = fmaf(vals[j], vals[j], p);
            p += __shfl_down(p, 2);
            p += __shfl_down(p, 1);
            if ((tid & 3) == 0) xxp2[(size_t)dt * S_DIM + st * 64 + s_row] = p;
        }
        {   // bf16 stage tile in fragment order
            int s_row = tid >> 2, dc = tid & 3;
            float vals[8];
#pragma unroll
            for (int j = 0; j < 8; ++j) vals[j] = ldsT[dc * 8 + j][s_row];
            unsigned int w[4];
#pragma unroll
            for (int q = 0; q < 4; ++q)
                w[q] = (unsigned int)f2bf(vals[2 * q]) | ((unsigned int)f2bf(vals[2 * q + 1]) << 16);
            int gn = ((s_row >> 5) << 1) | ((s_row >> 4) & 1);
            int c_dst = gn * 64 + dc * 16 + (s_row & 15);
            char* tile = Xstage + (size_t)st * 524288 + (size_t)dt * 4096;
            *(uint4*)(tile + (size_t)c_dst * 16) = make_uint4(w[0], w[1], w[2], w[3]);
        }
    }
}

// ---------------- combine partials + init best sentinels ----------------
__global__ __launch_bounds__(256) void k_sums(const float* __restrict__ eep, const float* __restrict__ xxp2,
                                              float* __restrict__ ee, float* __restrict__ xx,
                                              unsigned long long* __restrict__ best) {
    const int gid = blockIdx.x * 256 + threadIdx.x;
    if (gid < 1024) best[gid] = 0xFFFFFFFFFFFFFFFFull;
    if (gid < K_DIM) {
        float a = 0.f;
        for (int dt = 0; dt < 128; ++dt) a += eep[(size_t)dt * K_DIM + gid];
        ee[gid] = a;
    } else if (gid < K_DIM + S_DIM) {
        const int s = gid - K_DIM;
        float a = 0.f;
        for (int dt = 0; dt < 128; ++dt) a += xxp2[(size_t)dt * S_DIM + s];
        xx[s] = a;
    }
}

// ---------------- MFMA filter GEMM v5 (round-16 best): in-block K-split x4, 16 waves ----------------
__global__ __launch_bounds__(1024) void k_gemm_score5(const char* __restrict__ Estage, const char* __restrict__ Xstage,
                                                      const float* __restrict__ xx, const float* __restrict__ ee,
                                                      float* __restrict__ minp, int* __restrict__ cnt,
                                                      int* __restrict__ kcand, float* __restrict__ scand) {
    __shared__ short lds[4 * 3 * 6144];   // 147456 B; reused as f32x4 for acc reduce
    __shared__ float minw[2][64];
    __shared__ float minb[64];
    __shared__ int cntl[64];

    // XCD swizzle: 4 ktb x 8 st per XCD (bijective)
    const int linear = blockIdx.y * 16 + blockIdx.x;
    const int xcd = linear & 7, ii = linear >> 3;      // ii in [0,32)
    const int ktb = (xcd >> 1) * 4 + (ii >> 3);
    const int st  = (xcd & 1) * 8 + (ii & 7);

    const int tid = threadIdx.x;       // 0..1023
    const int h = tid >> 8;            // K-quarter 0..3
    const int tidh = tid & 255;
    const int wid2 = tidh >> 6;
    const int wm = wid2 >> 1;          // k half (64)
    const int wn = wid2 & 1;           // s half (32)
    const int lane = tid & 63;
    const int lr = lane & 15;
    const int lh = lane >> 4;

    const char* Eb = Estage + (size_t)ktb * 1048576;
    const char* Xb = Xstage + (size_t)st * 524288;
    short* myl = lds + h * 18432;      // this quarter's 3 slots x 6144 shorts

    f32x4 acc[4][2];
#pragma unroll
    for (int f = 0; f < 4; ++f)
#pragma unroll
        for (int g = 0; g < 2; ++g) acc[f][g] = (f32x4){0.f, 0.f, 0.f, 0.f};

#define STG(t, sl) { \
    const char* eb_ = Eb + (size_t)(h * 32 + (t)) * 8192; \
    char* d_ = (char*)myl + (sl) * 12288; \
    gload16(eb_ + tidh * 16, d_ + tidh * 16); \
    gload16(eb_ + 4096 + tidh * 16, d_ + 4096 + tidh * 16); \
    gload16(Xb + (size_t)(h * 32 + (t)) * 4096 + tidh * 16, d_ + 8192 + tidh * 16); }

#define CMP(sl) { \
    const short* s_ = myl + (sl) * 6144; \
    bf16x8 af[4], bx[2]; \
    _Pragma("unroll") \
    for (int f = 0; f < 4; ++f) af[f] = *(const bf16x8*)(s_ + (wm * 4 + f) * 512 + lane * 8); \
    _Pragma("unroll") \
    for (int g = 0; g < 2; ++g) bx[g] = *(const bf16x8*)(s_ + 4096 + (wn * 2 + g) * 512 + lane * 8); \
    _Pragma("unroll") \
    for (int f = 0; f < 4; ++f) { \
        _Pragma("unroll") \
        for (int g = 0; g < 2; ++g) \
            acc[f][g] = __builtin_amdgcn_mfma_f32_16x16x32_bf16(af[f], bx[g], acc[f][g], 0, 0, 0); \
    } }

#define WB(nstr) asm volatile("s_waitcnt vmcnt(" nstr ")\n\ts_barrier" ::: "memory")
#define BAR asm volatile("s_barrier" ::: "memory")

    STG(0, 0) STG(1, 1)

    for (int bb = 0; bb < 30; bb += 3) {
        STG(bb + 2, 2) WB("6"); CMP(0) BAR;
        STG(bb + 3, 0) WB("6"); CMP(1) BAR;
        STG(bb + 4, 1) WB("6"); CMP(2) BAR;
    }
    // staged 0..31, computed 0..29
    WB("3"); CMP(0) BAR;   // c30
    WB("0"); CMP(1)        // c31
    __syncthreads();

#undef STG
#undef CMP
#undef WB
#undef BAR

    // cross-quarter acc reduction via LDS (fixed ascending order, deterministic)
    f32x4* red4 = (f32x4*)lds;
    if (h != 0) {
#pragma unroll
        for (int f = 0; f < 4; ++f)
#pragma unroll
            for (int g = 0; g < 2; ++g)
                red4[(size_t)(h - 1) * 2048 + (f * 2 + g) * 256 + tidh] = acc[f][g];
    }
    __syncthreads();
    if (h == 0) {
#pragma unroll
        for (int q = 1; q < 4; ++q)
#pragma unroll
            for (int f = 0; f < 4; ++f)
#pragma unroll
                for (int g = 0; g < 2; ++g)
                    acc[f][g] += red4[(size_t)(q - 1) * 2048 + (f * 2 + g) * 256 + tidh];
    }

    // epilogue (round-10, validated): sc = (xx - 2*xe) + ee
    float xs[2], ek[4][4];
#pragma unroll
    for (int g = 0; g < 2; ++g) xs[g] = xx[st * 64 + wn * 32 + g * 16 + lr];
#pragma unroll
    for (int f = 0; f < 4; ++f)
#pragma unroll
        for (int r = 0; r < 4; ++r) ek[f][r] = ee[ktb * 128 + wm * 64 + f * 16 + lh * 4 + r];

    float mg[2] = {FLT_BIG, FLT_BIG};
#pragma unroll
    for (int f = 0; f < 4; ++f)
#pragma unroll
        for (int g = 0; g < 2; ++g)
#pragma unroll
            for (int r = 0; r < 4; ++r) {
                float sc = (xs[g] - 2.0f * acc[f][g][r]) + ek[f][r];
                mg[g] = fminf(mg[g], sc);
            }
#pragma unroll
    for (int g = 0; g < 2; ++g) {
        mg[g] = fminf(mg[g], __shfl_xor(mg[g], 16));
        mg[g] = fminf(mg[g], __shfl_xor(mg[g], 32));
    }
    if (h == 0 && lane < 16) {
        minw[wm][wn * 32 + lane] = mg[0];
        minw[wm][wn * 32 + 16 + lane] = mg[1];
    }
    __syncthreads();
    if (tid < 64) {
        float mb = fminf(minw[0][tid], minw[1][tid]);
        minb[tid] = mb;
        minp[ktb * S_DIM + st * 64 + tid] = mb;
        cntl[tid] = 0;
    }
    __syncthreads();
    if (h == 0) {
#pragma unroll
        for (int f = 0; f < 4; ++f)
#pragma unroll
            for (int g = 0; g < 2; ++g)
#pragma unroll
                for (int r = 0; r < 4; ++r) {
                    float sc = (xs[g] - 2.0f * acc[f][g][r]) + ek[f][r];
                    int sl = wn * 32 + g * 16 + lr;
                    if (sc <= minb[sl] + MARGIN) {
                        int slot = atomicAdd(&cntl[sl], 1);
                        if (slot < 32) {
                            int si = ktb * S_DIM + st * 64 + sl;
                            kcand[si * 32 + slot] = ktb * 128 + wm * 64 + f * 16 + lh * 4 + r;
                            scand[si * 32 + slot] = sc;
                        }
                    }
                }
    }
    __syncthreads();
    if (tid < 64) cnt[ktb * S_DIM + st * 64 + tid] = min(cntl[tid], 32);
}

// ---------------- gate: confident shortcut or emit PRUNED (s,k) pairs ----------------
__global__ __launch_bounds__(64) void k_select_gate(const float* __restrict__ minp, const int* __restrict__ cnt,
                                                    const int* __restrict__ kcand, const float* __restrict__ scand,
                                                    int* __restrict__ idx, float* __restrict__ out,
                                                    int* __restrict__ npairs, int2* __restrict__ pairs) {
    __shared__ int   lcand[64];
    __shared__ float lsc[64];
    __shared__ int   lcount;
    const int s = blockIdx.x;
    const int lane = threadIdx.x;
    if (lane == 0) lcount = 0;

    float mv = (lane < 16) ? minp[lane * S_DIM + s] : FLT_BIG;
#pragma unroll
    for (int off = 1; off < 64; off <<= 1) mv = fminf(mv, __shfl_xor(mv, off));
    const float m_a = mv;

    int myc = (lane < 16) ? cnt[lane * S_DIM + s] : 0;
    float gsc[16]; int gkc[16]; int gcs[16];
#pragma unroll
    for (int kt = 0; kt < 16; ++kt) {
        int c = __shfl(myc, kt);
        gcs[kt] = c;
        gsc[kt] = FLT_BIG; gkc[kt] = 0;
        if (lane < c) {
            gsc[kt] = scand[(kt * S_DIM + s) * 32 + lane];
            gkc[kt] = kcand[(kt * S_DIM + s) * 32 + lane];
        }
    }
#pragma unroll
    for (int kt = 0; kt < 16; ++kt) {
        if (lane < gcs[kt] && gsc[kt] <= m_a + MARGIN) {
            int slot = atomicAdd(&lcount, 1);
            if (slot < 64) { lcand[slot] = gkc[kt]; lsc[slot] = gsc[kt]; }
        }
    }
    __syncthreads();
    const int n = min(lcount, 64);

    float bv = (lane < n) ? lsc[lane] : FLT_BIG;
    int   bk = (lane < n) ? lcand[lane] : 0x7fffffff;
#pragma unroll
    for (int off = 1; off < 64; off <<= 1) {
        float ov = __shfl_xor(bv, off); int ok = __shfl_xor(bk, off);
        if (ov < bv || (ov == bv && ok < bk)) { bv = ov; bk = ok; }
    }
    float sv = (lane < n && lcand[lane] != bk) ? lsc[lane] : FLT_BIG;
#pragma unroll
    for (int off = 1; off < 64; off <<= 1) sv = fminf(sv, __shfl_xor(sv, off));

    if (n == 1 || sv - bv > CONF_GAP) {
        if (lane == 0) { idx[s] = bk; out[OUT_IDX + s] = (float)bk; }
        return;
    }

    bool em = (lane < n) && (lsc[lane] <= bv + CONF_GAP);
    unsigned long long m = __ballot(em);
    int cnt2 = __popcll(m);
    int base = 0;
    if (lane == 0) base = atomicAdd(npairs, cnt2);
    base = __shfl(base, 0);
    int off2 = (int)__popcll(m & ((1ull << lane) - 1ull));
    if (em) pairs[base + off2] = make_int2(s, lcand[lane]);
}

// ---------------- per-pair exact chain (bitwise round-0 arithmetic, register-resident) ----------------
__global__ __launch_bounds__(64) void k_pair_chain(const float* __restrict__ AT, const float* __restrict__ E,
                                                   const float* __restrict__ xx, const float* __restrict__ ee,
                                                   const int* __restrict__ npairs, const int2* __restrict__ pairs,
                                                   unsigned long long* __restrict__ best) {
    const int np = min(*npairs, 65536);
    const int lane = threadIdx.x;
    for (int p = blockIdx.x; p < np; p += gridDim.x) {
        int2 pr = pairs[p];
        const float4* er4 = (const float4*)(E + (size_t)pr.y * D_DIM) + lane * 16;
        const float4* xr4 = (const float4*)(AT + (size_t)pr.x * D_DIM) + lane * 16;
        float4 er[16], xr[16];
#pragma unroll
        for (int i = 0; i < 16; ++i) { er[i] = er4[i]; xr[i] = xr4[i]; }

        float c = 0.f;
        for (int seg = 0; seg < 64; ++seg) {
            float cin = __shfl(c, (seg + 63) & 63);
            if (lane == seg) {
                float a = (seg == 0) ? 0.f : cin;
#pragma unroll
                for (int i = 0; i < 16; ++i) {
                    a = fmaf(er[i].x, xr[i].x, a);
                    a = fmaf(er[i].y, xr[i].y, a);
                    a = fmaf(er[i].z, xr[i].z, a);
                    a = fmaf(er[i].w, xr[i].w, a);
                }
                c = a;
            }
        }
        float dot = __shfl(c, 63);
        if (lane == 0) {
            float u = xx[pr.x] - 2.0f * dot;
            float sc = u + ee[pr.y];
            unsigned long long pk = ((unsigned long long)__float_as_uint(sc) << 32) | (unsigned int)pr.y;
            atomicMin(&best[pr.x], pk);
        }
    }
}

// ---------------- Round-0 fallback GEMM+argmin ----------------
__global__ __launch_bounds__(256) void k_gemm_argmin(const float* __restrict__ A, const float* __restrict__ E,
                                                     const float* __restrict__ xx, const float* __restrict__ ee,
                                                     float* __restrict__ minv, int* __restrict__ mini) {
    __shared__ float Et[32][64];
    __shared__ float At[32][64];
    __shared__ float rv[16][64];
    __shared__ int   ri[16][64];
    const int kt = blockIdx.x, st = blockIdx.y;
    const int k0 = kt * 64, s0 = st * 64;
    const int tid = threadIdx.x;
    const int tcol = tid & 15, trow = tid >> 4;
    float acc[4][4] = {{0.f,0.f,0.f,0.f},{0.f,0.f,0.f,0.f},{0.f,0.f,0.f,0.f},{0.f,0.f,0.f,0.f}};
    for (int dt = 0; dt < D_DIM / 32; ++dt) {
        const int d0 = dt * 32;
        __syncthreads();
#pragma unroll
        for (int it = 0; it < 2; ++it) {
            int f = tid + it * 256;
            int kk = f >> 3, dd4 = f & 7;
            float4 v = *(const float4*)(E + (size_t)(k0 + kk) * D_DIM + d0 + dd4 * 4);
            Et[dd4 * 4 + 0][kk] = v.x; Et[dd4 * 4 + 1][kk] = v.y;
            Et[dd4 * 4 + 2][kk] = v.z; Et[dd4 * 4 + 3][kk] = v.w;
        }
#pragma unroll
        for (int it = 0; it < 2; ++it) {
            int f = tid + it * 256;
            int ss4 = f & 15, dd = f >> 4;
            float4 v = *(const float4*)(A + (size_t)(d0 + dd) * S_DIM + s0 + ss4 * 4);
            *(float4*)&At[dd][ss4 * 4] = v;
        }
        __syncthreads();
#pragma unroll 8
        for (int dd = 0; dd < 32; ++dd) {
            float4 a4 = *(const float4*)&At[dd][tcol * 4];
            float4 e4 = *(const float4*)&Et[dd][trow * 4];
            float a[4] = {a4.x, a4.y, a4.z, a4.w};
            float e[4] = {e4.x, e4.y, e4.z, e4.w};
#pragma unroll
            for (int i = 0; i < 4; ++i)
#pragma unroll
                for (int j = 0; j < 4; ++j) acc[i][j] = fmaf(e[i], a[j], acc[i][j]);
        }
    }
    float xs[4], ek[4];
#pragma unroll
    for (int j = 0; j < 4; ++j) xs[j] = xx[s0 + tcol * 4 + j];
#pragma unroll
    for (int i = 0; i < 4; ++i) ek[i] = ee[k0 + trow * 4 + i];
#pragma unroll
    for (int j = 0; j < 4; ++j) {
        float bv = FLT_BIG; int bk = 0x7fffffff;
#pragma unroll
        for (int i = 0; i < 4; ++i) {
            float xe = acc[i][j];
            float u = xs[j] - 2.0f * xe;
            float sc = u + ek[i];
            int k = k0 + trow * 4 + i;
            if (sc < bv) { bv = sc; bk = k; }
        }
        rv[trow][tcol * 4 + j] = bv;
        ri[trow][tcol * 4 + j] = bk;
    }
    __syncthreads();
    if (tid < 64) {
        float bv = rv[0][tid]; int bk = ri[0][tid];
#pragma unroll
        for (int r = 1; r < 16; ++r) {
            float v = rv[r][tid]; int k2 = ri[r][tid];
            if (v < bv || (v == bv && k2 < bk)) { bv = v; bk = k2; }
        }
        minv[kt * S_DIM + s0 + tid] = bv;
        mini[kt * S_DIM + s0 + tid] = bk;
    }
}

__global__ __launch_bounds__(256) void k_argmin_final(const float* __restrict__ minv, const int* __restrict__ mini,
                                                      int* __restrict__ idx, float* __restrict__ out) {
    const int s = blockIdx.x * 256 + threadIdx.x;
    float bv = minv[s];
    int bk = mini[s];
    for (int kt = 1; kt < 32; ++kt) {
        float v = minv[kt * S_DIM + s];
        int k2 = mini[kt * S_DIM + s];
        if (v < bv || (v == bv && k2 < bk)) { bv = v; bk = k2; }
    }
    idx[s] = bk;
    out[OUT_IDX + s] = (float)bk;
}

// ---------------- STE output + loss + fused fin: 256-d tiles, 1KB E-gather granules ----------------
__global__ __launch_bounds__(256) void k_output_loss2(const float* __restrict__ A, const float* __restrict__ E,
                                                      const int* __restrict__ idx,
                                                      const unsigned long long* __restrict__ best,
                                                      float* __restrict__ out, float* __restrict__ loss) {
    __shared__ float qt[64][261];   // 66.8 KB
    __shared__ int sidx[64];
    __shared__ float red[256];
    const int st = blockIdx.x, db = blockIdx.y;
    const int s0 = st * 64, d0 = db * 256;
    const int tid = threadIdx.x;
    if (tid < 64) {
        const int s = s0 + tid;
        unsigned long long b = best[s];
        int k;
        if (b != 0xFFFFFFFFFFFFFFFFull) {
            k = (int)(b & 0xFFFFFFFFu);
            if (db == 0) out[OUT_IDX + s] = (float)k;   // non-confident s: fin fused here
        } else {
            k = idx[s];                                  // confident s: gate wrote idx+out
        }
        sidx[tid] = k;
    }
    __syncthreads();
    // stage 64 rows x 256 floats: chunk c = i*256+tid; one E row per wave-instruction (1KB)
#pragma unroll
    for (int i = 0; i < 16; ++i) {
        int c = i * 256 + tid;
        int si = c >> 6, c4 = c & 63;
        float4 v = *(const float4*)(E + (size_t)sidx[si] * D_DIM + d0 + c4 * 4);
        qt[si][c4 * 4 + 0] = v.x; qt[si][c4 * 4 + 1] = v.y;
        qt[si][c4 * 4 + 2] = v.z; qt[si][c4 * 4 + 3] = v.w;
    }
    __syncthreads();
    const int ss = tid & 63;
    const int dg = tid >> 6;
    float lsum = 0.f;
#pragma unroll 8
    for (int i = 0; i < 64; ++i) {
        const int dd = dg * 64 + i;
        const int d = d0 + dd;
        float x = A[(size_t)d * S_DIM + s0 + ss];
        float q = qt[ss][dd];
        float diff = q - x;
        float val = x + diff;
        out[OUT_Q + (size_t)d * S_DIM + s0 + ss] = val;
        lsum = fmaf(diff, diff, lsum);
    }
    red[tid] = lsum;
    __syncthreads();
    for (int off = 128; off > 0; off >>= 1) {
        if (tid < off) red[tid] += red[tid + off];
        __syncthreads();
    }
    if (tid == 0) atomicAdd(loss, red[0]);
}

// ---------------- fallback STE output + loss ----------------
__global__ __launch_bounds__(256) void k_output_loss(const float* __restrict__ A, const float* __restrict__ E,
                                                     const int* __restrict__ idx, float* __restrict__ out,
                                                     float* __restrict__ loss) {
    __shared__ float qt[64][65];
    __shared__ int sidx[64];
    __shared__ float red[256];
    const int st = blockIdx.x, dtb = blockIdx.y;
    const int s0 = st * 64, d0 = dtb * 64;
    const int tid = threadIdx.x;
    if (tid < 64) sidx[tid] = idx[s0 + tid];
    __syncthreads();
#pragma unroll
    for (int it = 0; it < 4; ++it) {
        int f = tid + it * 256;
        int si = f >> 4, c4 = f & 15;
        float4 v = *(const float4*)(E + (size_t)sidx[si] * D_DIM + d0 + c4 * 4);
        qt[si][c4 * 4 + 0] = v.x; qt[si][c4 * 4 + 1] = v.y;
        qt[si][c4 * 4 + 2] = v.z; qt[si][c4 * 4 + 3] = v.w;
    }
    __syncthreads();
    const int ss = tid & 63;
    const int dg = tid >> 6;
    float lsum = 0.f;
#pragma unroll
    for (int i = 0; i < 16; ++i) {
        const int dd = dg * 16 + i;
        const int d = d0 + dd;
        float x = A[(size_t)d * S_DIM + s0 + ss];
        float q = qt[ss][dd];
        float diff = q - x;
        float val = x + diff;
        out[OUT_Q + (size_t)d * S_DIM + s0 + ss] = val;
        lsum = fmaf(diff, diff, lsum);
    }
    red[tid] = lsum;
    __syncthreads();
    for (int off = 128; off > 0; off >>= 1) {
        if (tid < off) red[tid] += red[tid + off];
        __syncthreads();
    }
    if (tid == 0) atomicAdd(loss, red[0]);
}

__global__ void k_scalars(const float* __restrict__ loss, float* __restrict__ out) {
    out[0] = 1.25f * loss[0] * (1.0f / (float)(S_DIM * D_DIM));
    out[OUT_PERP] = 1.0f;
}

extern "C" void kernel_launch(void* const* d_in, const int* in_sizes, int n_in,
                              void* d_out, int out_size, void* d_ws, size_t ws_size,
                              hipStream_t stream) {
    const float* A = (const float*)d_in[0];
    const float* E = (const float*)d_in[1];
    float* out = (float*)d_out;
    char* ws = (char*)d_ws;

    if (ws_size >= WS_NEEDED3) {
        float* w_loss = (float*)(ws + WS_LOSS);
        int*   w_np   = (int*)(ws + 16);
        float* w_xx   = (float*)(ws + WS_XX);
        float* w_ee   = (float*)(ws + WS_EE);
        float* w_minp = (float*)(ws + WS_MINP);
        int*   w_cnt  = (int*)(ws + WS_CNT);
        int*   w_idx  = (int*)(ws + WS_IDX);
        int*   w_kc   = (int*)(ws + WS_KCAND);
        float* w_sc   = (float*)(ws + WS_SCAND);
        char*  w_es   = ws + WS_ESTAGE;
        char*  w_xs   = ws + WS_XSTAGE;
        unsigned long long* w_best = (unsigned long long*)(ws + WS_BEST);
        int2*  w_pairs = (int2*)(ws + WS_PAIRS);
        float* w_eep  = (float*)(ws + WS_EEP);
        float* w_xxp2 = (float*)(ws + WS_XXP2);
        float* AT     = out + OUT_Q;   // park A^T in quant region; overwritten by k_output_loss2

        hipMemsetAsync(ws, 0, 64, stream);                     // loss + npairs
        k_conv<<<dim3(128, 32), 256, 0, stream>>>(E, A, AT, w_es, w_xs, w_eep, w_xxp2);
        k_sums<<<dim3(12), 256, 0, stream>>>(w_eep, w_xxp2, w_ee, w_xx, w_best);
        k_gemm_score5<<<dim3(16, 16), 1024, 0, stream>>>(w_es, w_xs, w_xx, w_ee, w_minp, w_cnt, w_kc, w_sc);
        k_select_gate<<<dim3(S_DIM), 64, 0, stream>>>(w_minp, w_cnt, w_kc, w_sc, w_idx, out, w_np, w_pairs);
        k_pair_chain<<<dim3(2048), 64, 0, stream>>>(AT, E, w_xx, w_ee, w_np, w_pairs, w_best);
        k_output_loss2<<<dim3(16, 16), 256, 0, stream>>>(A, E, w_idx, w_best, out, w_loss);
        k_scalars<<<1, 1, 0, stream>>>(w_loss, out);
    } else {
        // round-0 fallback
        float* w_loss = (float*)(ws + FB_LOSS);
        float* w_xx   = (float*)(ws + FB_XX);
        float* w_ee   = (float*)(ws + FB_EE);
        float* w_xxp  = (float*)(ws + FB_XXP);
        float* w_minv = (float*)(ws + FB_MINV);
        int*   w_mini = (int*)(ws + FB_MINI);
        int*   w_idx  = (int*)(ws + FB_IDX);

        hipMemsetAsync(ws, 0, 256, stream);
        k_xx_part<<<dim3(16, 4), 256, 0, stream>>>(A, w_xxp);
        k_ee<<<dim3(K_DIM), 256, 0, stream>>>(E, w_ee);
        k_xx_comb<<<dim3(4), 256, 0, stream>>>(w_xxp, w_xx);
        k_gemm_argmin<<<dim3(32, 16), 256, 0, stream>>>(A, E, w_xx, w_ee, w_minv, w_mini);
        k_argmin_final<<<dim3(4), 256, 0, stream>>>(w_minv, w_mini, w_idx, out);
        k_output_loss<<<dim3(16, 64), 256, 0, stream>>>(A, E, w_idx, out, w_loss);
        k_scalars<<<1, 1, 0, stream>>>(w_loss, out);
    }
}